// Round 8
// baseline (600.234 us; speedup 1.0000x reference)
//
#include <hip/hip_runtime.h>
#include <cmath>

// ---------------------------------------------------------------------------
// Performer (FAVOR+) attention, fp32, MI355X.
// Algebra: ratio cancels; k-side stabilizer S applied post-hoc (exp range safe);
// q-side rowmax applied post-hoc.
//   qph = exp(qd - diag_q)                (unstabilized)
//   U[m][e] = sum_n exp(kd - diag_k) v ;  u[m] = sum_n exp(kd - diag_k)
//   ctx'[m][e] = (e^-S U + eps sv[e]) / L ; kmean'[m] = e^-S u / L + eps
//   out = (A + eps e^{rm} Sc) / (B + eps e^{rm} Sk)
//
// R8 changes (LDS-pipe relief on pass_k main):
//  - R7 post-mortem: counted-vmcnt pipeline + conflict fix were NEUTRAL ->
//    pass_k is LDS-issue-bound (~192 ds_read_b128 /wave/sc on one LDS pipe).
//  - GEMM1's PT operand now read from GLOBAL (L2-resident, sc-invariant,
//    shared by all blocks) with a register ring-1 — exactly pass_q's GEMM1
//    pattern. Removes 64 LDS reads/wave/sc AND the 16KB PTs LDS buffer.
//  - Pool 37.9KB -> 4 blocks/CU. R6 barrier structure restored (no wrap
//    re-read); R7's conflict-free epilogue kept (FA=vS, FB=kS scratch).
//  - Tail path / pass_q / combine unchanged (bitwise-identical results).
// ---------------------------------------------------------------------------

namespace {
constexpr float NORM       = 0.35355339059327379f; // 64^-0.25
constexpr float DIAG_SCALE = 0.0625f;              // 0.5 * 64^-0.5
constexpr float EPSV       = 1e-4f;
constexpr float INV_L      = 1.0f / 4096.0f;

// workspace layout (float offsets)
constexpr size_t OFF_PT  = 0;                          // PT[64][272]
constexpr size_t OFF_U   = OFF_PT + (size_t)64 * 272;  // U[32][272][64]
constexpr size_t OFF_u   = OFF_U + (size_t)32 * 272 * 64; // u[32][272]
constexpr size_t OFF_SV  = OFF_u + (size_t)32 * 272;   // sv[32][64]
constexpr size_t OFF_SC  = OFF_SV + (size_t)32 * 64;   // Sc[32][64]
constexpr size_t OFF_SK  = OFF_SC + (size_t)32 * 64;   // Sk[32]
constexpr size_t OFF_S   = OFF_SK + 32;                // S (1, encoded uint)
constexpr size_t OFF_CTX = OFF_S + 4;                  // ctx_ext[32][272][68]
constexpr size_t WS_FLOATS = OFF_CTX + (size_t)32 * 272 * 68;
} // namespace

__device__ __forceinline__ unsigned fenc(float f) {
  unsigned u = __float_as_uint(f);
  return (u & 0x80000000u) ? ~u : (u | 0x80000000u);
}
__device__ __forceinline__ float fdec(unsigned u) {
  return (u & 0x80000000u) ? __uint_as_float(u ^ 0x80000000u) : __uint_as_float(~u);
}

// async global->LDS: per-lane global src, wave-uniform LDS base (+lane*size)
__device__ __forceinline__ void glds4(const float* g, float* l) {
  __builtin_amdgcn_global_load_lds((const __attribute__((address_space(1))) void*)g,
                                   (__attribute__((address_space(3))) void*)l, 4, 0, 0);
}
__device__ __forceinline__ void glds16(const float* g, float* l) {
  __builtin_amdgcn_global_load_lds((const __attribute__((address_space(1))) void*)g,
                                   (__attribute__((address_space(3))) void*)l, 16, 0, 0);
}

// --------------------------- K0: setup -------------------------------------
__global__ __launch_bounds__(256) void setup_kernel(const float* __restrict__ P,
                                                    float* __restrict__ ws) {
  const int t = threadIdx.x;
  const int elem = blockIdx.x * 256 + t; // < 64*272 exactly (grid 68)
  const int td = elem / 272, mm = elem % 272;
  ws[OFF_PT + (size_t)td * 272 + mm] = (mm < 266) ? NORM * P[mm * 64 + td] : 0.0f;
  if (blockIdx.x == 0 && t == 0) ((unsigned*)(ws + OFF_S))[0] = 0x007FFFFFu; // enc(-inf)
}

// per-row GEMM1 micro-step: row acc a1r[4] += K4 components * p0..p3 (16 FMA)
#define KQ_ROW(A1R, K4, P0, P1, P2, P3)                                         \
  {                                                                             \
    A1R[0] = fmaf((K4).x, (P0).x, A1R[0]);                                      \
    A1R[1] = fmaf((K4).x, (P0).y, A1R[1]);                                      \
    A1R[2] = fmaf((K4).x, (P0).z, A1R[2]);                                      \
    A1R[3] = fmaf((K4).x, (P0).w, A1R[3]);                                      \
    A1R[0] = fmaf((K4).y, (P1).x, A1R[0]);                                      \
    A1R[1] = fmaf((K4).y, (P1).y, A1R[1]);                                      \
    A1R[2] = fmaf((K4).y, (P1).z, A1R[2]);                                      \
    A1R[3] = fmaf((K4).y, (P1).w, A1R[3]);                                      \
    A1R[0] = fmaf((K4).z, (P2).x, A1R[0]);                                      \
    A1R[1] = fmaf((K4).z, (P2).y, A1R[1]);                                      \
    A1R[2] = fmaf((K4).z, (P2).z, A1R[2]);                                      \
    A1R[3] = fmaf((K4).z, (P2).w, A1R[3]);                                      \
    A1R[0] = fmaf((K4).w, (P3).x, A1R[0]);                                      \
    A1R[1] = fmaf((K4).w, (P3).y, A1R[1]);                                      \
    A1R[2] = fmaf((K4).w, (P3).z, A1R[2]);                                      \
    A1R[3] = fmaf((K4).w, (P3).w, A1R[3]);                                      \
  }

// GEMM2 micro-step: row acc AR[4] += Q4 components * c0..c3
#define QC_ROW(AR, Q4, C0, C1, C2, C3)                                          \
  {                                                                             \
    AR[0] = fmaf((Q4).x, (C0).x, AR[0]);                                        \
    AR[1] = fmaf((Q4).x, (C0).y, AR[1]);                                        \
    AR[2] = fmaf((Q4).x, (C0).z, AR[2]);                                        \
    AR[3] = fmaf((Q4).x, (C0).w, AR[3]);                                        \
    AR[0] = fmaf((Q4).y, (C1).x, AR[0]);                                        \
    AR[1] = fmaf((Q4).y, (C1).y, AR[1]);                                        \
    AR[2] = fmaf((Q4).y, (C1).z, AR[2]);                                        \
    AR[3] = fmaf((Q4).y, (C1).w, AR[3]);                                        \
    AR[0] = fmaf((Q4).z, (C2).x, AR[0]);                                        \
    AR[1] = fmaf((Q4).z, (C2).y, AR[1]);                                        \
    AR[2] = fmaf((Q4).z, (C2).z, AR[2]);                                        \
    AR[3] = fmaf((Q4).z, (C2).w, AR[3]);                                        \
    AR[0] = fmaf((Q4).w, (C3).x, AR[0]);                                        \
    AR[1] = fmaf((Q4).w, (C3).y, AR[1]);                                        \
    AR[2] = fmaf((Q4).w, (C3).z, AR[2]);                                        \
    AR[3] = fmaf((Q4).w, (C3).w, AR[3]);                                        \
  }

// --------------------------- K1: fused k-side pass ---------------------------
// grid (5, 32, 4):
//   x in [0,4)  : main k-pass, m-block = x (m in [0,256)), 1024 rows per z
//   x == 4      : tail k-pass (m in [256,266)) + sv accumulation
__global__ __launch_bounds__(256) void pass_k_fused(const float* __restrict__ kg,
                                                    const float* __restrict__ vg,
                                                    float* __restrict__ ws) {
  __shared__ __align__(16) float pool[9472]; // main: kS[4352]|vS[4096]
                                             // tail: PTt[1024]|kS[4352]|vS[4096]
  __shared__ float diagS[64];
  __shared__ float redb[4];

  const int t = threadIdx.x;
  const int mb = blockIdx.x, bh = blockIdx.y, bz = blockIdx.z;
  const int lane = t & 63, wv = t >> 6;

  const size_t base = ((size_t)bh * 4096 + (size_t)bz * 1024) * 64;

  if (mb == 4) {
    // =================== tail path: m in [256, 272) + sv ===================
    float* PTs = pool;          // PT_t[td 64][16]
    float* kS  = pool + 1024;   // k rows stride 68; reused as kp (stride 20)
    float* vSt = pool + 5376;   // v rows [64][64]
    const int m4 = t & 3, rg1 = t >> 2;          // GEMM1: 1 row, 4 m's
    const int eg = (t >> 2) & 15, rs = t >> 6;   // GEMM2: 4m x 4e x 4 n-quarters

    {
      const int td = t >> 2, m4i = t & 3;
      *(float4*)(PTs + td * 16 + m4i * 4) =
          *(const float4*)(ws + OFF_PT + (size_t)td * 272 + 256 + m4i * 4);
    }

    float acc2[4][4];
#pragma unroll
    for (int i = 0; i < 4; ++i) { acc2[i][0] = acc2[i][1] = acc2[i][2] = acc2[i][3] = 0.f; }
    float uacc[4] = {0, 0, 0, 0};
    float vsum[4] = {0, 0, 0, 0};
    float smax = -INFINITY;

    for (int sc = 0; sc < 16; ++sc) {
      const float* kgp = kg + base + (size_t)sc * 64 * 64;
      const float* vgp = vg + base + (size_t)sc * 64 * 64;
      __syncthreads();
      {
        const int r0 = wv * 16;
#pragma unroll
        for (int r = 0; r < 16; ++r) glds4(kgp + (r0 + r) * 64 + lane, kS + (r0 + r) * 68);
#pragma unroll
        for (int r4 = 0; r4 < 4; ++r4)
          glds16(vgp + (r0 + r4 * 4) * 64 + lane * 4, vSt + (r0 + r4 * 4) * 64);
      }
      __syncthreads();
      {
        const int dr = t >> 2, dq = t & 3;
        const float4 s0 = *(const float4*)(kS + dr * 68 + dq * 16);
        const float4 s1 = *(const float4*)(kS + dr * 68 + dq * 16 + 4);
        const float4 s2 = *(const float4*)(kS + dr * 68 + dq * 16 + 8);
        const float4 s3 = *(const float4*)(kS + dr * 68 + dq * 16 + 12);
        float s = s0.x * s0.x;
        s = fmaf(s0.y, s0.y, s); s = fmaf(s0.z, s0.z, s); s = fmaf(s0.w, s0.w, s);
        s = fmaf(s1.x, s1.x, s); s = fmaf(s1.y, s1.y, s); s = fmaf(s1.z, s1.z, s);
        s = fmaf(s1.w, s1.w, s);
        s = fmaf(s2.x, s2.x, s); s = fmaf(s2.y, s2.y, s); s = fmaf(s2.z, s2.z, s);
        s = fmaf(s2.w, s2.w, s);
        s = fmaf(s3.x, s3.x, s); s = fmaf(s3.y, s3.y, s); s = fmaf(s3.z, s3.z, s);
        s = fmaf(s3.w, s3.w, s);
        s += __shfl_xor(s, 1);
        s += __shfl_xor(s, 2);
        if (dq == 0) diagS[dr] = s * DIAG_SCALE;
      }
      __syncthreads();
      float a1[4] = {0, 0, 0, 0};
#pragma unroll
      for (int tb = 0; tb < 16; ++tb) {
        const int td = tb * 4;
        const float4 kv4 = *(const float4*)(kS + rg1 * 68 + td);
        const float4 p0 = *(const float4*)(PTs + (td + 0) * 16 + m4 * 4);
        const float4 p1 = *(const float4*)(PTs + (td + 1) * 16 + m4 * 4);
        const float4 p2 = *(const float4*)(PTs + (td + 2) * 16 + m4 * 4);
        const float4 p3 = *(const float4*)(PTs + (td + 3) * 16 + m4 * 4);
        KQ_ROW(a1, kv4, p0, p1, p2, p3);
      }
      float vals[4];
      {
        const float dg = diagS[rg1];
#pragma unroll
        for (int j = 0; j < 4; ++j) {
          const int m = 256 + m4 * 4 + j;
          float e = 0.f;
          if (m < 266) {
            smax = fmaxf(smax, a1[j]);
            e = __expf(a1[j] - dg);
          }
          vals[j] = e;
        }
      }
      __syncthreads();
      {
        float4 st;
        st.x = vals[0]; st.y = vals[1]; st.z = vals[2]; st.w = vals[3];
        *(float4*)(kS + rg1 * 20 + m4 * 4) = st;
      }
      __syncthreads();
#pragma unroll 2
      for (int nn = 0; nn < 16; ++nn) {
        const int n = rs * 16 + nn;
        const float4 kk4 = *(const float4*)(kS + n * 20 + m4 * 4);
        const float4 vv4 = *(const float4*)(vSt + n * 64 + eg * 4);
        const float kk[4] = {kk4.x, kk4.y, kk4.z, kk4.w};
        const float vv[4] = {vv4.x, vv4.y, vv4.z, vv4.w};
#pragma unroll
        for (int i = 0; i < 4; ++i)
#pragma unroll
          for (int j = 0; j < 4; ++j) acc2[i][j] = fmaf(kk[i], vv[j], acc2[i][j]);
        if (eg == 0) {
#pragma unroll
          for (int i = 0; i < 4; ++i) uacc[i] += kk[i];
        }
        if (m4 == 0) {
          vsum[0] += vv[0]; vsum[1] += vv[1]; vsum[2] += vv[2]; vsum[3] += vv[3];
        }
      }
    }
    {
      float* Ub = ws + OFF_U + ((size_t)bh * 272 + 256 + m4 * 4) * 64 + eg * 4;
#pragma unroll
      for (int i = 0; i < 4; ++i)
#pragma unroll
        for (int j = 0; j < 4; ++j) atomicAdd(Ub + (size_t)i * 64 + j, acc2[i][j]);
      if (eg == 0) {
#pragma unroll
        for (int i = 0; i < 4; ++i)
          atomicAdd(ws + OFF_u + (size_t)bh * 272 + 256 + m4 * 4 + i, uacc[i]);
      }
      if (m4 == 0) {
#pragma unroll
        for (int j = 0; j < 4; ++j)
          atomicAdd(ws + OFF_SV + bh * 64 + eg * 4 + j, vsum[j]);
      }
    }
#pragma unroll
    for (int o = 32; o > 0; o >>= 1) smax = fmaxf(smax, __shfl_xor(smax, o));
    if (lane == 0) redb[wv] = smax;
    __syncthreads();
    if (t == 0) {
      const float m = fmaxf(fmaxf(redb[0], redb[1]), fmaxf(redb[2], redb[3]));
      atomicMax((unsigned*)(ws + OFF_S), fenc(m));
    }
    return;
  }

  // =================== main path: m-block mb, m in [0,256) ===================
  float* kS = pool;          // k rows [row 64][d] stride 68; reused as kp, scratch
  float* vS = pool + 4352;   // v rows [row 64][e 64] stride 64; reused as scratch

  const int mq = t & 15, rg = t >> 4;          // GEMM1: 16 m-quads x 16 row-groups(4)
  const int mo = t & 7, eo = (t >> 3) & 7;     // GEMM2: 8 m-octs x 8 e-octs
  const int rs = t >> 6;                       // GEMM2: n quarter (= wave id)

  float acc2[8][8];
#pragma unroll
  for (int i = 0; i < 8; ++i)
#pragma unroll
    for (int j = 0; j < 8; ++j) acc2[i][j] = 0.f;
  float uacc[8] = {0, 0, 0, 0, 0, 0, 0, 0};
  float smax = -INFINITY;

  const float* ptm = ws + OFF_PT + mb * 64 + mq * 4; // PT column base (L2-hot)

  for (int sc = 0; sc < 16; ++sc) {
    const float* kgp = kg + base + (size_t)sc * 64 * 64;
    const float* vgp = vg + base + (size_t)sc * 64 * 64;
    __syncthreads(); // previous iter's LDS reads complete
    {
      const int r0 = wv * 16;
#pragma unroll
      for (int r = 0; r < 16; ++r) glds4(kgp + (r0 + r) * 64 + lane, kS + (r0 + r) * 68);
#pragma unroll
      for (int r4 = 0; r4 < 4; ++r4)
        glds16(vgp + (r0 + r4 * 4) * 64 + lane * 4, vS + (r0 + r4 * 4) * 64);
    }
    __syncthreads(); // staged (vmcnt drained by barrier)
    // diag pre-phase: row t>>2, quarter t&3
    {
      const int dr = t >> 2, dq = t & 3;
      const float4 s0 = *(const float4*)(kS + dr * 68 + dq * 16);
      const float4 s1 = *(const float4*)(kS + dr * 68 + dq * 16 + 4);
      const float4 s2 = *(const float4*)(kS + dr * 68 + dq * 16 + 8);
      const float4 s3 = *(const float4*)(kS + dr * 68 + dq * 16 + 12);
      float s = s0.x * s0.x;
      s = fmaf(s0.y, s0.y, s); s = fmaf(s0.z, s0.z, s); s = fmaf(s0.w, s0.w, s);
      s = fmaf(s1.x, s1.x, s); s = fmaf(s1.y, s1.y, s); s = fmaf(s1.z, s1.z, s);
      s = fmaf(s1.w, s1.w, s);
      s = fmaf(s2.x, s2.x, s); s = fmaf(s2.y, s2.y, s); s = fmaf(s2.z, s2.z, s);
      s = fmaf(s2.w, s2.w, s);
      s = fmaf(s3.x, s3.x, s); s = fmaf(s3.y, s3.y, s); s = fmaf(s3.z, s3.z, s);
      s = fmaf(s3.w, s3.w, s);
      s += __shfl_xor(s, 1);
      s += __shfl_xor(s, 2);
      if (dq == 0) diagS[dr] = s * DIAG_SCALE;
    }
    __syncthreads(); // diagS ready

    // GEMM1: kd[rows 4][m 4]; k from LDS (broadcast), PT from global ring-1
    float a1[4][4];
#pragma unroll
    for (int i = 0; i < 4; ++i) { a1[i][0] = a1[i][1] = a1[i][2] = a1[i][3] = 0.f; }
    {
      float4 pf0 = *(const float4*)(ptm + (size_t)0 * 272);
      float4 pf1 = *(const float4*)(ptm + (size_t)1 * 272);
      float4 pf2 = *(const float4*)(ptm + (size_t)2 * 272);
      float4 pf3 = *(const float4*)(ptm + (size_t)3 * 272);
#pragma unroll
      for (int tb = 0; tb < 16; ++tb) {
        const int td = tb * 4;
        const float4 kA = *(const float4*)(kS + (rg * 4 + 0) * 68 + td);
        const float4 kB = *(const float4*)(kS + (rg * 4 + 1) * 68 + td);
        const float4 kC = *(const float4*)(kS + (rg * 4 + 2) * 68 + td);
        const float4 kD = *(const float4*)(kS + (rg * 4 + 3) * 68 + td);
        const float4 c0 = pf0, c1 = pf1, c2 = pf2, c3 = pf3;
        if (tb < 15) {
          pf0 = *(const float4*)(ptm + (size_t)(td + 4) * 272);
          pf1 = *(const float4*)(ptm + (size_t)(td + 5) * 272);
          pf2 = *(const float4*)(ptm + (size_t)(td + 6) * 272);
          pf3 = *(const float4*)(ptm + (size_t)(td + 7) * 272);
        }
        KQ_ROW(a1[0], kA, c0, c1, c2, c3);
        KQ_ROW(a1[1], kB, c0, c1, c2, c3);
        KQ_ROW(a1[2], kC, c0, c1, c2, c3);
        KQ_ROW(a1[3], kD, c0, c1, c2, c3);
      }
    }
    // smax on raw kd, then exp in-place
#pragma unroll
    for (int i = 0; i < 4; ++i) {
      const float dg = diagS[rg * 4 + i];
      smax = fmaxf(smax, fmaxf(fmaxf(a1[i][0], a1[i][1]), fmaxf(a1[i][2], a1[i][3])));
      a1[i][0] = __expf(a1[i][0] - dg);
      a1[i][1] = __expf(a1[i][1] - dg);
      a1[i][2] = __expf(a1[i][2] - dg);
      a1[i][3] = __expf(a1[i][3] - dg);
    }
    __syncthreads(); // all kS reads done -> overwrite with kp
#pragma unroll
    for (int i = 0; i < 4; ++i) {
      float4 st;
      st.x = a1[i][0]; st.y = a1[i][1]; st.z = a1[i][2]; st.w = a1[i][3];
      *(float4*)(kS + (rg * 4 + i) * 68 + mq * 4) = st; // kp[row][m] stride 68
    }
    __syncthreads(); // kp ready
    // GEMM2: U_partial[8m][8e] += kp^T * v (n split by wave)
#pragma unroll 2
    for (int nn = 0; nn < 16; ++nn) {
      const int n = rs * 16 + nn;
      const float4 ka = *(const float4*)(kS + n * 68 + mo * 8);
      const float4 kb = *(const float4*)(kS + n * 68 + mo * 8 + 4);
      const float4 va = *(const float4*)(vS + n * 64 + eo * 8);
      const float4 vb = *(const float4*)(vS + n * 64 + eo * 8 + 4);
      const float kk[8] = {ka.x, ka.y, ka.z, ka.w, kb.x, kb.y, kb.z, kb.w};
      const float vv[8] = {va.x, va.y, va.z, va.w, vb.x, vb.y, vb.z, vb.w};
#pragma unroll
      for (int i = 0; i < 8; ++i)
#pragma unroll
        for (int j = 0; j < 8; ++j) acc2[i][j] = fmaf(kk[i], vv[j], acc2[i][j]);
      if (eo == 0) {
#pragma unroll
        for (int i = 0; i < 8; ++i) uacc[i] += kk[i];
      }
    }
  }

  // ---- epilogue: fold 4 waves' acc2, then line-coalesced atomics ----
  __syncthreads(); // all GEMM2 reads done; kS/vS free as scratch
  {
    float* FA = vS; // fold scratch [accidx 64][lane 64]
    float* FB = kS; // fold scratch [accidx 64][lane 64] (first 4096 floats)
    if (wv == 1) {
#pragma unroll
      for (int i = 0; i < 8; ++i)
#pragma unroll
        for (int j = 0; j < 8; ++j) FA[(i * 8 + j) * 64 + lane] = acc2[i][j];
    }
    if (wv == 3) {
#pragma unroll
      for (int i = 0; i < 8; ++i)
#pragma unroll
        for (int j = 0; j < 8; ++j) FB[(i * 8 + j) * 64 + lane] = acc2[i][j];
    }
    __syncthreads();
    if (wv == 0) {
#pragma unroll
      for (int i = 0; i < 8; ++i)
#pragma unroll
        for (int j = 0; j < 8; ++j) acc2[i][j] += FA[(i * 8 + j) * 64 + lane];
    }
    if (wv == 2) {
#pragma unroll
      for (int i = 0; i < 8; ++i)
#pragma unroll
        for (int j = 0; j < 8; ++j) acc2[i][j] += FB[(i * 8 + j) * 64 + lane];
    }
    __syncthreads();
    if (wv == 2) {
#pragma unroll
      for (int i = 0; i < 8; ++i)
#pragma unroll
        for (int j = 0; j < 8; ++j) FA[(i * 8 + j) * 64 + lane] = acc2[i][j];
    }
    __syncthreads();
    if (wv == 0) {
      // final sums, producer-lane-contiguous: kS[lane][idx] stride 65 (2-way max)
#pragma unroll
      for (int i = 0; i < 8; ++i)
#pragma unroll
        for (int j = 0; j < 8; ++j) {
          acc2[i][j] += FA[(i * 8 + j) * 64 + lane];
          kS[lane * 65 + i * 8 + j] = acc2[i][j];
        }
    }
    __syncthreads();
    // line-coalesced atomics: each wave handles 16 contiguous U rows
    {
      float* Ub = ws + OFF_U + ((size_t)bh * 272 + mb * 64) * 64;
#pragma unroll
      for (int r = 0; r < 16; ++r) {
        const int row = wv * 16 + r;
        const int lp = (row >> 3) + 8 * (lane >> 3);      // producer lane
        const int idx = (row & 7) * 8 + (lane & 7);       // producer index
        atomicAdd(Ub + (size_t)row * 64 + lane, kS[lp * 65 + idx]);
      }
    }
    if (eo == 0) {
#pragma unroll
      for (int i = 0; i < 8; ++i)
        atomicAdd(ws + OFF_u + (size_t)bh * 272 + mb * 64 + mo * 8 + i, uacc[i]);
    }
  }
#pragma unroll
  for (int o = 32; o > 0; o >>= 1) smax = fmaxf(smax, __shfl_xor(smax, o));
  if (lane == 0) redb[wv] = smax;
  __syncthreads();
  if (t == 0) {
    const float m = fmaxf(fmaxf(redb[0], redb[1]), fmaxf(redb[2], redb[3]));
    atomicMax((unsigned*)(ws + OFF_S), fenc(m));
  }
}

// --------------------------- K3: combine -> ctx_ext, Sc, Sk -----------------
__global__ __launch_bounds__(256) void combine_kernel(float* __restrict__ ws) {
  __shared__ float red[256];
  const int t = threadIdx.x;
  const int bh = blockIdx.x;
  const float S = fdec(((unsigned*)(ws + OFF_S))[0]);
  const float es = __expf(-S);
  const int e = t & 63, mr = t >> 6;
  const float svv = ws[OFF_SV + bh * 64 + e];
  float scp = 0.f;
  for (int mm = mr; mm < 272; mm += 4) {
    float val = 0.f;
    if (mm < 266)
      val = (es * ws[OFF_U + ((size_t)bh * 272 + mm) * 64 + e] + EPSV * svv) * INV_L;
    ws[OFF_CTX + ((size_t)bh * 272 + mm) * 68 + e] = val;
    scp += val;
  }
  red[t] = scp;
  __syncthreads();
  if (t < 64) ws[OFF_SC + bh * 64 + t] = red[t] + red[t + 64] + red[t + 128] + red[t + 192];
  __syncthreads();
  float skp = 0.f;
  for (int mm = t; mm < 272; mm += 256) {
    float km = 0.f;
    if (mm < 266) km = es * ws[OFF_u + (size_t)bh * 272 + mm] * INV_L + EPSV;
    float* cx = ws + OFF_CTX + ((size_t)bh * 272 + mm) * 68;
    cx[64] = km; cx[65] = 0.f; cx[66] = 0.f; cx[67] = 0.f;
    skp += km;
  }
  red[t] = skp;
  __syncthreads();
  for (int s = 128; s > 0; s >>= 1) {
    if (t < s) red[t] += red[t + s];
    __syncthreads();
  }
  if (t == 0) ws[OFF_SK + bh] = red[0];
}

// --------------------------- K4: q-pass -> out ------------------------------
// LDS: uni = qS[32][68] + PTt[64][16]@2176 during GEMM1, then qph[32][272],
// then reduction scratch for GEMM2.
__global__ __launch_bounds__(256) void pass_q(const float* __restrict__ qg,
                                              float* __restrict__ outg,
                                              const float* __restrict__ ws) {
  __shared__ __align__(16) float uni[8704];
  __shared__ float diagS[32];
  __shared__ unsigned rmx[32];
  __shared__ float Bl[32];

  const int t = threadIdx.x;
  const int nt = blockIdx.x, bh = blockIdx.y;
  const int lane = t & 63, wv = t >> 6;
  const float* qgp = qg + ((size_t)bh * 4096 + (size_t)nt * 32) * 64;

  if (t < 32) rmx[t] = 0x007FFFFFu; // enc(-inf)

  // stage qS[32][68] via GLDS (rows wv*8..wv*8+7); qS occupies uni[0..2172)
#pragma unroll
  for (int r = 0; r < 8; ++r)
    glds4(qgp + (wv * 8 + r) * 64 + lane, uni + (wv * 8 + r) * 68);
  // stage tail PT[64][16] into uni[2176..3200)
  {
    const int td = t >> 2, j4 = t & 3;
    *(float4*)(uni + 2176 + td * 16 + j4 * 4) =
        *(const float4*)(ws + OFF_PT + (size_t)td * 272 + 256 + j4 * 4);
  }
  __syncthreads();

  // diag pre-phase: row t>>3 (32 rows), eighth t&7
  {
    const int dr = t >> 3, d8 = t & 7;
    const float4 s0 = *(const float4*)(uni + dr * 68 + d8 * 8);
    const float4 s1 = *(const float4*)(uni + dr * 68 + d8 * 8 + 4);
    float s = s0.x * s0.x;
    s = fmaf(s0.y, s0.y, s); s = fmaf(s0.z, s0.z, s); s = fmaf(s0.w, s0.w, s);
    s = fmaf(s1.x, s1.x, s); s = fmaf(s1.y, s1.y, s); s = fmaf(s1.z, s1.z, s);
    s = fmaf(s1.w, s1.w, s);
    s += __shfl_xor(s, 1);
    s += __shfl_xor(s, 2);
    s += __shfl_xor(s, 4);
    if (d8 == 0) diagS[dr] = s * DIAG_SCALE;
  }
  __syncthreads();

  // GEMM1 main: mq = lane (64 m-quads, m<256); rows wv*8..+7; PT ring-2 (8 rows)
  const int mq = t & 63;
  float a1[8][4];
#pragma unroll
  for (int i = 0; i < 8; ++i) { a1[i][0] = a1[i][1] = a1[i][2] = a1[i][3] = 0.f; }
  {
    const float* ptm = ws + OFF_PT + mq * 4;
    float4 pfA0, pfA1, pfA2, pfA3, pfB0, pfB1, pfB2, pfB3;
    pfA0 = *(const float4*)(ptm + (size_t)0 * 272);
    pfA1 = *(const float4*)(ptm + (size_t)1 * 272);
    pfA2 = *(const float4*)(ptm + (size_t)2 * 272);
    pfA3 = *(const float4*)(ptm + (size_t)3 * 272);
    pfB0 = *(const float4*)(ptm + (size_t)4 * 272);
    pfB1 = *(const float4*)(ptm + (size_t)5 * 272);
    pfB2 = *(const float4*)(ptm + (size_t)6 * 272);
    pfB3 = *(const float4*)(ptm + (size_t)7 * 272);
#pragma unroll
    for (int tb = 0; tb < 16; tb += 2) {
      {
        const int td = tb * 4;
#pragma unroll
        for (int i = 0; i < 8; ++i) {
          const float4 q4 = *(const float4*)(uni + (wv * 8 + i) * 68 + td);
          KQ_ROW(a1[i], q4, pfA0, pfA1, pfA2, pfA3);
        }
        if (tb < 14) {
          pfA0 = *(const float4*)(ptm + (size_t)(td + 8) * 272);
          pfA1 = *(const float4*)(ptm + (size_t)(td + 9) * 272);
          pfA2 = *(const float4*)(ptm + (size_t)(td + 10) * 272);
          pfA3 = *(const float4*)(ptm + (size_t)(td + 11) * 272);
        }
      }
      {
        const int td = tb * 4 + 4;
#pragma unroll
        for (int i = 0; i < 8; ++i) {
          const float4 q4 = *(const float4*)(uni + (wv * 8 + i) * 68 + td);
          KQ_ROW(a1[i], q4, pfB0, pfB1, pfB2, pfB3);
        }
        if (tb < 14) {
          pfB0 = *(const float4*)(ptm + (size_t)(td + 8) * 272);
          pfB1 = *(const float4*)(ptm + (size_t)(td + 9) * 272);
          pfB2 = *(const float4*)(ptm + (size_t)(td + 10) * 272);
          pfB3 = *(const float4*)(ptm + (size_t)(td + 11) * 272);
        }
      }
    }
  }
  // GEMM1 tail: m_t = 256 + (t&15), rows r2, r2+1; PTt from LDS
  float at[2] = {0.f, 0.f};
  const int mtl = t & 15;
  const int mt = 256 + mtl;
  const int r2 = (t >> 4) * 2;
  {
    const float* pts = uni + 2176 + mtl;
#pragma unroll
    for (int tb = 0; tb < 16; ++tb) {
      const int td = tb * 4;
      const float4 qx4 = *(const float4*)(uni + r2 * 68 + td);
      const float4 qy4 = *(const float4*)(uni + (r2 + 1) * 68 + td);
      const float p0 = pts[(td + 0) * 16];
      const float p1 = pts[(td + 1) * 16];
      const float p2 = pts[(td + 2) * 16];
      const float p3 = pts[(td + 3) * 16];
      at[0] = fmaf(qx4.x, p0, at[0]);
      at[0] = fmaf(qx4.y, p1, at[0]);
      at[0] = fmaf(qx4.z, p2, at[0]);
      at[0] = fmaf(qx4.w, p3, at[0]);
      at[1] = fmaf(qy4.x, p0, at[1]);
      at[1] = fmaf(qy4.y, p1, at[1]);
      at[1] = fmaf(qy4.z, p2, at[1]);
      at[1] = fmaf(qy4.w, p3, at[1]);
    }
  }
  __syncthreads(); // all qS/PTt reads complete -> uni can be rewritten as qph

  // rowmax (raw qd): main butterfly + tail group-reduce, into LDS atomicMax
#pragma unroll
  for (int i = 0; i < 8; ++i) {
    float lm = fmaxf(fmaxf(a1[i][0], a1[i][1]), fmaxf(a1[i][2], a1[i][3]));
#pragma unroll
    for (int o = 32; o > 0; o >>= 1) lm = fmaxf(lm, __shfl_xor(lm, o));
    if (lane == i) atomicMax(&rmx[wv * 8 + i], fenc(lm));
  }
#pragma unroll
  for (int s = 0; s < 2; ++s) {
    float v = (mt < 266) ? at[s] : -INFINITY;
#pragma unroll
    for (int o = 8; o > 0; o >>= 1) v = fmaxf(v, __shfl_xor(v, o));
    if ((t & 15) == 0) atomicMax(&rmx[r2 + s], fenc(v));
  }
  // exp (unstabilized, diag from LDS) + store qph (stride 272)
#pragma unroll
  for (int i = 0; i < 8; ++i) {
    const int row = wv * 8 + i;
    const float dg = diagS[row];
    float4 st;
    st.x = __expf(a1[i][0] - dg);
    st.y = __expf(a1[i][1] - dg);
    st.z = __expf(a1[i][2] - dg);
    st.w = __expf(a1[i][3] - dg);
    *(float4*)(uni + row * 272 + mq * 4) = st;
  }
#pragma unroll
  for (int s = 0; s < 2; ++s) {
    const int row = r2 + s;
    uni[row * 272 + mt] = (mt < 266) ? __expf(at[s] - diagS[row]) : 0.f;
  }
  __syncthreads();

  // GEMM2: 4 rows x 4 cols x m-split(2). cq2 = e-quad, rg2 = 4-row group,
  // ms = m-half. ctx streamed from global (L2-resident) with ring-1 prefetch.
  const int cq2 = t & 15, rg2 = (t >> 4) & 7, ms = t >> 7;
  const float* ctxg = ws + OFF_CTX + (size_t)bh * 272 * 68;
  const float* crow = ctxg + cq2 * 4;
  const int mb0 = ms * 136;
  float acc[4][4];
#pragma unroll
  for (int i = 0; i < 4; ++i) { acc[i][0] = acc[i][1] = acc[i][2] = acc[i][3] = 0.f; }
  float accB[4] = {0, 0, 0, 0};
  float4 c0, c1, c2, c3, n0, n1, n2, n3;
  float cb0 = 0, cb1 = 0, cb2 = 0, cb3 = 0, nb0 = 0, nb1 = 0, nb2 = 0, nb3 = 0;
  c0 = *(const float4*)(crow + (size_t)(mb0 + 0) * 68);
  c1 = *(const float4*)(crow + (size_t)(mb0 + 1) * 68);
  c2 = *(const float4*)(crow + (size_t)(mb0 + 2) * 68);
  c3 = *(const float4*)(crow + (size_t)(mb0 + 3) * 68);
  if (cq2 == 0) {
    cb0 = ctxg[(size_t)(mb0 + 0) * 68 + 64];
    cb1 = ctxg[(size_t)(mb0 + 1) * 68 + 64];
    cb2 = ctxg[(size_t)(mb0 + 2) * 68 + 64];
    cb3 = ctxg[(size_t)(mb0 + 3) * 68 + 64];
  }
  for (int mc = 0; mc < 34; ++mc) {
    const int mm = mb0 + mc * 4;
    if (mc < 33) {
      n0 = *(const float4*)(crow + (size_t)(mm + 4) * 68);
      n1 = *(const float4*)(crow + (size_t)(mm + 5) * 68);
      n2 = *(const float4*)(crow + (size_t)(mm + 6) * 68);
      n3 = *(const float4*)(crow + (size_t)(mm + 7) * 68);
      if (cq2 == 0) {
        nb0 = ctxg[(size_t)(mm + 4) * 68 + 64];
        nb1 = ctxg[(size_t)(mm + 5) * 68 + 64];
        nb2 = ctxg[(size_t)(mm + 6) * 68 + 64];
        nb3 = ctxg[(size_t)(mm + 7) * 68 + 64];
      }
    }
    const float4 q0 = *(const float4*)(uni + (rg2 * 4 + 0) * 272 + mm);
    const float4 q1 = *(const float4*)(uni + (rg2 * 4 + 1) * 272 + mm);
    const float4 q2 = *(const float4*)(uni + (rg2 * 4 + 2) * 272 + mm);
    const float4 q3 = *(const float4*)(uni + (rg2 * 4 + 3) * 272 + mm);
    QC_ROW(acc[0], q0, c0, c1, c2, c3);
    QC_ROW(acc[1], q1, c0, c1, c2, c3);
    QC_ROW(acc[2], q2, c0, c1, c2, c3);
    QC_ROW(acc[3], q3, c0, c1, c2, c3);
    if (cq2 == 0) {
      accB[0] = fmaf(q0.x, cb0, accB[0]);
      accB[0] = fmaf(q0.y, cb1, accB[0]);
      accB[0] = fmaf(q0.z, cb2, accB[0]);
      accB[0] = fmaf(q0.w, cb3, accB[0]);
      accB[1] = fmaf(q1.x, cb0, accB[1]);
      accB[1] = fmaf(q1.y, cb1, accB[1]);
      accB[1] = fmaf(q1.z, cb2, accB[1]);
      accB[1] = fmaf(q1.w, cb3, accB[1]);
      accB[2] = fmaf(q2.x, cb0, accB[2]);
      accB[2] = fmaf(q2.y, cb1, accB[2]);
      accB[2] = fmaf(q2.z, cb2, accB[2]);
      accB[2] = fmaf(q2.w, cb3, accB[2]);
      accB[3] = fmaf(q3.x, cb0, accB[3]);
      accB[3] = fmaf(q3.y, cb1, accB[3]);
      accB[3] = fmaf(q3.z, cb2, accB[3]);
      accB[3] = fmaf(q3.w, cb3, accB[3]);
    }
    if (mc < 33) {
      c0 = n0; c1 = n1; c2 = n2; c3 = n3;
      cb0 = nb0; cb1 = nb1; cb2 = nb2; cb3 = nb3;
    }
  }

  // reduce the two m-halves through LDS (qph dead now), stride-1 layout
  __syncthreads(); // all qph reads complete
  if (ms == 1) {
    const int p = t - 128;
#pragma unroll
    for (int i = 0; i < 4; ++i)
#pragma unroll
      for (int j = 0; j < 4; ++j) uni[(i * 4 + j) * 128 + p] = acc[i][j];
    if (cq2 == 0) {
#pragma unroll
      for (int i = 0; i < 4; ++i) uni[2048 + rg2 * 4 + i] = accB[i];
    }
  }
  __syncthreads();
  if (ms == 0) {
#pragma unroll
    for (int i = 0; i < 4; ++i)
#pragma unroll
      for (int j = 0; j < 4; ++j) acc[i][j] += uni[(i * 4 + j) * 128 + t];
    if (cq2 == 0) {
#pragma unroll
      for (int i = 0; i < 4; ++i) Bl[rg2 * 4 + i] = accB[i] + uni[2048 + rg2 * 4 + i];
    }
  }
  __syncthreads(); // Bl ready

  if (ms == 0) {
    const float4 sc4 = *(const float4*)(ws + OFF_SC + bh * 64 + cq2 * 4);
    const float skv = ws[OFF_SK + bh];
    float* op = outg + ((size_t)bh * 4096 + (size_t)nt * 32) * 64;
#pragma unroll
    for (int i = 0; i < 4; ++i) {
      const int row = rg2 * 4 + i;
      const float rm = fdec(rmx[row]);
      const float tt = EPSV * __expf(rm);
      const float inv = 1.0f / (Bl[row] + tt * skv);
      float4 o;
      o.x = (acc[i][0] + tt * sc4.x) * inv;
      o.y = (acc[i][1] + tt * sc4.y) * inv;
      o.z = (acc[i][2] + tt * sc4.z) * inv;
      o.w = (acc[i][3] + tt * sc4.w) * inv;
      *(float4*)(op + row * 64 + cq2 * 4) = o;
    }
  }
}

// --------------------------- launch -----------------------------------------
extern "C" void kernel_launch(void* const* d_in, const int* in_sizes, int n_in,
                              void* d_out, int out_size, void* d_ws, size_t ws_size,
                              hipStream_t stream) {
  (void)in_sizes; (void)n_in; (void)out_size; (void)ws_size;
  const float* q = (const float*)d_in[0];
  const float* k = (const float*)d_in[1];
  const float* v = (const float*)d_in[2];
  const float* P = (const float*)d_in[3];
  float* out = (float*)d_out;
  float* ws = (float*)d_ws;

  // zero only the accumulated region [OFF_U, OFF_CTX)
  hipMemsetAsync((void*)(ws + OFF_U), 0, (OFF_CTX - OFF_U) * sizeof(float), stream);
  setup_kernel<<<68, 256, 0, stream>>>(P, ws);
  pass_k_fused<<<dim3(5, 32, 4), 256, 0, stream>>>(k, v, ws);
  combine_kernel<<<32, 256, 0, stream>>>(ws);
  pass_q<<<dim3(128, 32), 256, 0, stream>>>(q, out, ws);
}

// Round 9
// 484.202 us; speedup vs baseline: 1.2396x; 1.2396x over previous
//
#include <hip/hip_runtime.h>
#include <cmath>

// ---------------------------------------------------------------------------
// Performer (FAVOR+) attention, fp32, MI355X.
// Algebra: ratio cancels; k-side stabilizer S applied post-hoc (exp range safe);
// q-side rowmax applied post-hoc.
//   qph = exp(qd - diag_q)                (unstabilized)
//   U[m][e] = sum_n exp(kd - diag_k) v ;  u[m] = sum_n exp(kd - diag_k)
//   ctx'[m][e] = (e^-S U + eps sv[e]) / L ; kmean'[m] = e^-S u / L + eps
//   out = (A + eps e^{rm} Sc) / (B + eps e^{rm} Sk)
//
// R9 changes:
//  - REVERT R8 (PT-from-global raised VGPR 116->172, occupancy -1/3, -43%).
//    pass_k main restored to R6 structure (PTs staged in LDS, pool 50.7KB)
//    with R7's conflict-free epilogue (producer-contiguous stage, 65K confl).
//  - NEW: XCD-aware block remap for pass_k. The 5 blocks reading the same
//    524KB k/v chunk (mb=0..4 of one (bh,bz)) were dispatched consecutively
//    -> round-robin across 8 XCDs -> 8 private-L2 copies (FETCH 165MB vs
//    67MB ideal). Remap g = xcd + 8*(mb + 5*cgrp), c = xcd + 8*cgrp,
//    bh = c&31, bz = c>>5: all blocks of a bh land on XCD bh%8 -> chunk
//    fetched once per XCD + U[bh] atomics stay on one XCD (no line
//    ping-pong). Bijective; correctness unaffected.
// ---------------------------------------------------------------------------

namespace {
constexpr float NORM       = 0.35355339059327379f; // 64^-0.25
constexpr float DIAG_SCALE = 0.0625f;              // 0.5 * 64^-0.5
constexpr float EPSV       = 1e-4f;
constexpr float INV_L      = 1.0f / 4096.0f;

// workspace layout (float offsets)
constexpr size_t OFF_PT  = 0;                          // PT[64][272]
constexpr size_t OFF_U   = OFF_PT + (size_t)64 * 272;  // U[32][272][64]
constexpr size_t OFF_u   = OFF_U + (size_t)32 * 272 * 64; // u[32][272]
constexpr size_t OFF_SV  = OFF_u + (size_t)32 * 272;   // sv[32][64]
constexpr size_t OFF_SC  = OFF_SV + (size_t)32 * 64;   // Sc[32][64]
constexpr size_t OFF_SK  = OFF_SC + (size_t)32 * 64;   // Sk[32]
constexpr size_t OFF_S   = OFF_SK + 32;                // S (1, encoded uint)
constexpr size_t OFF_CTX = OFF_S + 4;                  // ctx_ext[32][272][68]
constexpr size_t WS_FLOATS = OFF_CTX + (size_t)32 * 272 * 68;
} // namespace

__device__ __forceinline__ unsigned fenc(float f) {
  unsigned u = __float_as_uint(f);
  return (u & 0x80000000u) ? ~u : (u | 0x80000000u);
}
__device__ __forceinline__ float fdec(unsigned u) {
  return (u & 0x80000000u) ? __uint_as_float(u ^ 0x80000000u) : __uint_as_float(~u);
}

// async global->LDS: per-lane global src, wave-uniform LDS base (+lane*size)
__device__ __forceinline__ void glds4(const float* g, float* l) {
  __builtin_amdgcn_global_load_lds((const __attribute__((address_space(1))) void*)g,
                                   (__attribute__((address_space(3))) void*)l, 4, 0, 0);
}
__device__ __forceinline__ void glds16(const float* g, float* l) {
  __builtin_amdgcn_global_load_lds((const __attribute__((address_space(1))) void*)g,
                                   (__attribute__((address_space(3))) void*)l, 16, 0, 0);
}

// --------------------------- K0: setup -------------------------------------
__global__ __launch_bounds__(256) void setup_kernel(const float* __restrict__ P,
                                                    float* __restrict__ ws) {
  const int t = threadIdx.x;
  const int elem = blockIdx.x * 256 + t; // < 64*272 exactly (grid 68)
  const int td = elem / 272, mm = elem % 272;
  ws[OFF_PT + (size_t)td * 272 + mm] = (mm < 266) ? NORM * P[mm * 64 + td] : 0.0f;
  if (blockIdx.x == 0 && t == 0) ((unsigned*)(ws + OFF_S))[0] = 0x007FFFFFu; // enc(-inf)
}

// per-row GEMM1 micro-step: row acc a1r[4] += K4 components * p0..p3 (16 FMA)
#define KQ_ROW(A1R, K4, P0, P1, P2, P3)                                         \
  {                                                                             \
    A1R[0] = fmaf((K4).x, (P0).x, A1R[0]);                                      \
    A1R[1] = fmaf((K4).x, (P0).y, A1R[1]);                                      \
    A1R[2] = fmaf((K4).x, (P0).z, A1R[2]);                                      \
    A1R[3] = fmaf((K4).x, (P0).w, A1R[3]);                                      \
    A1R[0] = fmaf((K4).y, (P1).x, A1R[0]);                                      \
    A1R[1] = fmaf((K4).y, (P1).y, A1R[1]);                                      \
    A1R[2] = fmaf((K4).y, (P1).z, A1R[2]);                                      \
    A1R[3] = fmaf((K4).y, (P1).w, A1R[3]);                                      \
    A1R[0] = fmaf((K4).z, (P2).x, A1R[0]);                                      \
    A1R[1] = fmaf((K4).z, (P2).y, A1R[1]);                                      \
    A1R[2] = fmaf((K4).z, (P2).z, A1R[2]);                                      \
    A1R[3] = fmaf((K4).z, (P2).w, A1R[3]);                                      \
    A1R[0] = fmaf((K4).w, (P3).x, A1R[0]);                                      \
    A1R[1] = fmaf((K4).w, (P3).y, A1R[1]);                                      \
    A1R[2] = fmaf((K4).w, (P3).z, A1R[2]);                                      \
    A1R[3] = fmaf((K4).w, (P3).w, A1R[3]);                                      \
  }

// GEMM2 micro-step: row acc AR[4] += Q4 components * c0..c3
#define QC_ROW(AR, Q4, C0, C1, C2, C3)                                          \
  {                                                                             \
    AR[0] = fmaf((Q4).x, (C0).x, AR[0]);                                        \
    AR[1] = fmaf((Q4).x, (C0).y, AR[1]);                                        \
    AR[2] = fmaf((Q4).x, (C0).z, AR[2]);                                        \
    AR[3] = fmaf((Q4).x, (C0).w, AR[3]);                                        \
    AR[0] = fmaf((Q4).y, (C1).x, AR[0]);                                        \
    AR[1] = fmaf((Q4).y, (C1).y, AR[1]);                                        \
    AR[2] = fmaf((Q4).y, (C1).z, AR[2]);                                        \
    AR[3] = fmaf((Q4).y, (C1).w, AR[3]);                                        \
    AR[0] = fmaf((Q4).z, (C2).x, AR[0]);                                        \
    AR[1] = fmaf((Q4).z, (C2).y, AR[1]);                                        \
    AR[2] = fmaf((Q4).z, (C2).z, AR[2]);                                        \
    AR[3] = fmaf((Q4).z, (C2).w, AR[3]);                                        \
    AR[0] = fmaf((Q4).w, (C3).x, AR[0]);                                        \
    AR[1] = fmaf((Q4).w, (C3).y, AR[1]);                                        \
    AR[2] = fmaf((Q4).w, (C3).z, AR[2]);                                        \
    AR[3] = fmaf((Q4).w, (C3).w, AR[3]);                                        \
  }

// --------------------------- K1: fused k-side pass ---------------------------
// grid: 640 blocks (1D), XCD-aware remap inside:
//   g = xcd + 8*(mb + 5*cgrp); c = xcd + 8*cgrp; bh = c&31, bz = c>>5.
//   mb in [0,4): main k-pass (m-block = mb); mb == 4: tail + sv.
__global__ __launch_bounds__(256) void pass_k_fused(const float* __restrict__ kg,
                                                    const float* __restrict__ vg,
                                                    float* __restrict__ ws) {
  __shared__ __align__(16) float pool[12544]; // PTs[4096] | kS[64*68] | vS[64*64]
  __shared__ float diagS[64];
  __shared__ float redb[4];

  const int t = threadIdx.x;
  // XCD-aware remap: all blocks of a given bh land on XCD bh%8.
  const int g = blockIdx.x;
  const int xcd = g & 7;
  const int r_ = g >> 3;
  const int mb = r_ % 5;
  const int cgrp = r_ / 5;
  const int c_ = xcd + 8 * cgrp;   // 0..127
  const int bh = c_ & 31, bz = c_ >> 5;

  const int lane = t & 63, wv = t >> 6;

  float* PTs = pool;          // main: PT tile [td 64][m 64]; tail: PT_t[td 64][16]
  float* kS  = pool + 4096;   // k rows [row 64][d] stride 68; reused as kp / scratch
  float* vS  = pool + 8448;   // v rows [row 64][e 64] stride 64; reused as scratch

  const size_t base = ((size_t)bh * 4096 + (size_t)bz * 1024) * 64;

  if (mb == 4) {
    // =================== tail path: m in [256, 272) + sv ===================
    const int m4 = t & 3, rg1 = t >> 2;          // GEMM1: 1 row, 4 m's
    const int eg = (t >> 2) & 15, rs = t >> 6;   // GEMM2: 4m x 4e x 4 n-quarters

    // stage PT_t[64][16] once
    {
      const int td = t >> 2, m4i = t & 3;
      *(float4*)(PTs + td * 16 + m4i * 4) =
          *(const float4*)(ws + OFF_PT + (size_t)td * 272 + 256 + m4i * 4);
    }

    float acc2[4][4];
#pragma unroll
    for (int i = 0; i < 4; ++i) { acc2[i][0] = acc2[i][1] = acc2[i][2] = acc2[i][3] = 0.f; }
    float uacc[4] = {0, 0, 0, 0};
    float vsum[4] = {0, 0, 0, 0};
    float smax = -INFINITY;

    for (int sc = 0; sc < 16; ++sc) {
      const float* kgp = kg + base + (size_t)sc * 64 * 64;
      const float* vgp = vg + base + (size_t)sc * 64 * 64;
      __syncthreads(); // previous iter's LDS reads complete
      {
        const int r0 = wv * 16;
#pragma unroll
        for (int r = 0; r < 16; ++r) glds4(kgp + (r0 + r) * 64 + lane, kS + (r0 + r) * 68);
#pragma unroll
        for (int r4 = 0; r4 < 4; ++r4)
          glds16(vgp + (r0 + r4 * 4) * 64 + lane * 4, vS + (r0 + r4 * 4) * 64);
      }
      __syncthreads(); // staged
      // diag pre-phase: row t>>2, quarter t&3
      {
        const int dr = t >> 2, dq = t & 3;
        const float4 s0 = *(const float4*)(kS + dr * 68 + dq * 16);
        const float4 s1 = *(const float4*)(kS + dr * 68 + dq * 16 + 4);
        const float4 s2 = *(const float4*)(kS + dr * 68 + dq * 16 + 8);
        const float4 s3 = *(const float4*)(kS + dr * 68 + dq * 16 + 12);
        float s = s0.x * s0.x;
        s = fmaf(s0.y, s0.y, s); s = fmaf(s0.z, s0.z, s); s = fmaf(s0.w, s0.w, s);
        s = fmaf(s1.x, s1.x, s); s = fmaf(s1.y, s1.y, s); s = fmaf(s1.z, s1.z, s);
        s = fmaf(s1.w, s1.w, s);
        s = fmaf(s2.x, s2.x, s); s = fmaf(s2.y, s2.y, s); s = fmaf(s2.z, s2.z, s);
        s = fmaf(s2.w, s2.w, s);
        s = fmaf(s3.x, s3.x, s); s = fmaf(s3.y, s3.y, s); s = fmaf(s3.z, s3.z, s);
        s = fmaf(s3.w, s3.w, s);
        s += __shfl_xor(s, 1);
        s += __shfl_xor(s, 2);
        if (dq == 0) diagS[dr] = s * DIAG_SCALE;
      }
      __syncthreads(); // diagS ready
      // GEMM1: row rg1, m-quad m4
      float a1[4] = {0, 0, 0, 0};
#pragma unroll
      for (int tb = 0; tb < 16; ++tb) {
        const int td = tb * 4;
        const float4 kv4 = *(const float4*)(kS + rg1 * 68 + td);
        const float4 p0 = *(const float4*)(PTs + (td + 0) * 16 + m4 * 4);
        const float4 p1 = *(const float4*)(PTs + (td + 1) * 16 + m4 * 4);
        const float4 p2 = *(const float4*)(PTs + (td + 2) * 16 + m4 * 4);
        const float4 p3 = *(const float4*)(PTs + (td + 3) * 16 + m4 * 4);
        KQ_ROW(a1, kv4, p0, p1, p2, p3);
      }
      float vals[4];
      {
        const float dg = diagS[rg1];
#pragma unroll
        for (int j = 0; j < 4; ++j) {
          const int m = 256 + m4 * 4 + j;
          float e = 0.f;
          if (m < 266) {
            smax = fmaxf(smax, a1[j]);
            e = __expf(a1[j] - dg);
          }
          vals[j] = e;
        }
      }
      __syncthreads(); // all kS reads done -> overwrite with kp (stride 20)
      {
        float4 st;
        st.x = vals[0]; st.y = vals[1]; st.z = vals[2]; st.w = vals[3];
        *(float4*)(kS + rg1 * 20 + m4 * 4) = st;
      }
      __syncthreads(); // kp ready
#pragma unroll 2
      for (int nn = 0; nn < 16; ++nn) {
        const int n = rs * 16 + nn;
        const float4 kk4 = *(const float4*)(kS + n * 20 + m4 * 4);
        const float4 vv4 = *(const float4*)(vS + n * 64 + eg * 4);
        const float kk[4] = {kk4.x, kk4.y, kk4.z, kk4.w};
        const float vv[4] = {vv4.x, vv4.y, vv4.z, vv4.w};
#pragma unroll
        for (int i = 0; i < 4; ++i)
#pragma unroll
          for (int j = 0; j < 4; ++j) acc2[i][j] = fmaf(kk[i], vv[j], acc2[i][j]);
        if (eg == 0) {
#pragma unroll
          for (int i = 0; i < 4; ++i) uacc[i] += kk[i];
        }
        if (m4 == 0) {
          vsum[0] += vv[0]; vsum[1] += vv[1]; vsum[2] += vv[2]; vsum[3] += vv[3];
        }
      }
    }
    {
      float* Ub = ws + OFF_U + ((size_t)bh * 272 + 256 + m4 * 4) * 64 + eg * 4;
#pragma unroll
      for (int i = 0; i < 4; ++i)
#pragma unroll
        for (int j = 0; j < 4; ++j) atomicAdd(Ub + (size_t)i * 64 + j, acc2[i][j]);
      if (eg == 0) {
#pragma unroll
        for (int i = 0; i < 4; ++i)
          atomicAdd(ws + OFF_u + (size_t)bh * 272 + 256 + m4 * 4 + i, uacc[i]);
      }
      if (m4 == 0) {
#pragma unroll
        for (int j = 0; j < 4; ++j)
          atomicAdd(ws + OFF_SV + bh * 64 + eg * 4 + j, vsum[j]);
      }
    }
#pragma unroll
    for (int o = 32; o > 0; o >>= 1) smax = fmaxf(smax, __shfl_xor(smax, o));
    if (lane == 0) redb[wv] = smax;
    __syncthreads();
    if (t == 0) {
      const float m = fmaxf(fmaxf(redb[0], redb[1]), fmaxf(redb[2], redb[3]));
      atomicMax((unsigned*)(ws + OFF_S), fenc(m));
    }
    return;
  }

  // =================== main path: m-block mb, m in [0,256) ===================
  const int mq = t & 15, rg = t >> 4;          // GEMM1: 16 m-quads x 16 row-groups(4)
  const int mo = t & 7, eo = (t >> 3) & 7;     // GEMM2: 8 m-octs x 8 e-octs
  const int rs = t >> 6;                       // GEMM2: n quarter (= wave id)

  // stage PTs[td 64][m 64] once (invariant over sc)
#pragma unroll
  for (int cidx = 0; cidx < 4; ++cidx) {
    const int f4 = cidx * 256 + t;
    const int td = f4 >> 4, mi = f4 & 15;
    *(float4*)(PTs + td * 64 + mi * 4) =
        *(const float4*)(ws + OFF_PT + (size_t)td * 272 + mb * 64 + mi * 4);
  }

  float acc2[8][8];
#pragma unroll
  for (int i = 0; i < 8; ++i)
#pragma unroll
    for (int j = 0; j < 8; ++j) acc2[i][j] = 0.f;
  float uacc[8] = {0, 0, 0, 0, 0, 0, 0, 0};
  float smax = -INFINITY;

  for (int sc = 0; sc < 16; ++sc) {
    const float* kgp = kg + base + (size_t)sc * 64 * 64;
    const float* vgp = vg + base + (size_t)sc * 64 * 64;
    __syncthreads(); // previous iter's LDS reads complete (also covers PTs staging)
    {
      const int r0 = wv * 16;
#pragma unroll
      for (int r = 0; r < 16; ++r) glds4(kgp + (r0 + r) * 64 + lane, kS + (r0 + r) * 68);
#pragma unroll
      for (int r4 = 0; r4 < 4; ++r4)
        glds16(vgp + (r0 + r4 * 4) * 64 + lane * 4, vS + (r0 + r4 * 4) * 64);
    }
    __syncthreads(); // staged (vmcnt drained by barrier)
    // diag pre-phase: row t>>2, quarter t&3
    {
      const int dr = t >> 2, dq = t & 3;
      const float4 s0 = *(const float4*)(kS + dr * 68 + dq * 16);
      const float4 s1 = *(const float4*)(kS + dr * 68 + dq * 16 + 4);
      const float4 s2 = *(const float4*)(kS + dr * 68 + dq * 16 + 8);
      const float4 s3 = *(const float4*)(kS + dr * 68 + dq * 16 + 12);
      float s = s0.x * s0.x;
      s = fmaf(s0.y, s0.y, s); s = fmaf(s0.z, s0.z, s); s = fmaf(s0.w, s0.w, s);
      s = fmaf(s1.x, s1.x, s); s = fmaf(s1.y, s1.y, s); s = fmaf(s1.z, s1.z, s);
      s = fmaf(s1.w, s1.w, s);
      s = fmaf(s2.x, s2.x, s); s = fmaf(s2.y, s2.y, s); s = fmaf(s2.z, s2.z, s);
      s = fmaf(s2.w, s2.w, s);
      s = fmaf(s3.x, s3.x, s); s = fmaf(s3.y, s3.y, s); s = fmaf(s3.z, s3.z, s);
      s = fmaf(s3.w, s3.w, s);
      s += __shfl_xor(s, 1);
      s += __shfl_xor(s, 2);
      if (dq == 0) diagS[dr] = s * DIAG_SCALE;
    }
    __syncthreads(); // diagS ready

    // GEMM1: kd[rows 4][m 4]
    float a1[4][4];
#pragma unroll
    for (int i = 0; i < 4; ++i) { a1[i][0] = a1[i][1] = a1[i][2] = a1[i][3] = 0.f; }
#pragma unroll
    for (int tb = 0; tb < 16; ++tb) {
      const int td = tb * 4;
      const float4 kA = *(const float4*)(kS + (rg * 4 + 0) * 68 + td);
      const float4 kB = *(const float4*)(kS + (rg * 4 + 1) * 68 + td);
      const float4 kC = *(const float4*)(kS + (rg * 4 + 2) * 68 + td);
      const float4 kD = *(const float4*)(kS + (rg * 4 + 3) * 68 + td);
      const float4 p0 = *(const float4*)(PTs + (td + 0) * 64 + mq * 4);
      const float4 p1 = *(const float4*)(PTs + (td + 1) * 64 + mq * 4);
      const float4 p2 = *(const float4*)(PTs + (td + 2) * 64 + mq * 4);
      const float4 p3 = *(const float4*)(PTs + (td + 3) * 64 + mq * 4);
      KQ_ROW(a1[0], kA, p0, p1, p2, p3);
      KQ_ROW(a1[1], kB, p0, p1, p2, p3);
      KQ_ROW(a1[2], kC, p0, p1, p2, p3);
      KQ_ROW(a1[3], kD, p0, p1, p2, p3);
    }
    // smax on raw kd, then exp in-place
#pragma unroll
    for (int i = 0; i < 4; ++i) {
      const float dg = diagS[rg * 4 + i];
      smax = fmaxf(smax, fmaxf(fmaxf(a1[i][0], a1[i][1]), fmaxf(a1[i][2], a1[i][3])));
      a1[i][0] = __expf(a1[i][0] - dg);
      a1[i][1] = __expf(a1[i][1] - dg);
      a1[i][2] = __expf(a1[i][2] - dg);
      a1[i][3] = __expf(a1[i][3] - dg);
    }
    __syncthreads(); // all kS reads done -> overwrite with kp
#pragma unroll
    for (int i = 0; i < 4; ++i) {
      float4 st;
      st.x = a1[i][0]; st.y = a1[i][1]; st.z = a1[i][2]; st.w = a1[i][3];
      *(float4*)(kS + (rg * 4 + i) * 68 + mq * 4) = st; // kp[row][m] stride 68
    }
    __syncthreads(); // kp ready
    // GEMM2: U_partial[8m][8e] += kp^T * v (n split by wave)
#pragma unroll 2
    for (int nn = 0; nn < 16; ++nn) {
      const int n = rs * 16 + nn;
      const float4 ka = *(const float4*)(kS + n * 68 + mo * 8);
      const float4 kb = *(const float4*)(kS + n * 68 + mo * 8 + 4);
      const float4 va = *(const float4*)(vS + n * 64 + eo * 8);
      const float4 vb = *(const float4*)(vS + n * 64 + eo * 8 + 4);
      const float kk[8] = {ka.x, ka.y, ka.z, ka.w, kb.x, kb.y, kb.z, kb.w};
      const float vv[8] = {va.x, va.y, va.z, va.w, vb.x, vb.y, vb.z, vb.w};
#pragma unroll
      for (int i = 0; i < 8; ++i)
#pragma unroll
        for (int j = 0; j < 8; ++j) acc2[i][j] = fmaf(kk[i], vv[j], acc2[i][j]);
      if (eo == 0) {
#pragma unroll
        for (int i = 0; i < 8; ++i) uacc[i] += kk[i];
      }
    }
  }

  // ---- epilogue: fold 4 waves' acc2, then line-coalesced atomics (R7) ----
  __syncthreads(); // all GEMM2 reads done; kS/vS/PTs free as scratch
  {
    float* FA = vS;  // fold scratch [accidx 64][lane 64]
    float* FB = PTs; // fold scratch [accidx 64][lane 64]
    if (wv == 1) {
#pragma unroll
      for (int i = 0; i < 8; ++i)
#pragma unroll
        for (int j = 0; j < 8; ++j) FA[(i * 8 + j) * 64 + lane] = acc2[i][j];
    }
    if (wv == 3) {
#pragma unroll
      for (int i = 0; i < 8; ++i)
#pragma unroll
        for (int j = 0; j < 8; ++j) FB[(i * 8 + j) * 64 + lane] = acc2[i][j];
    }
    __syncthreads();
    if (wv == 0) {
#pragma unroll
      for (int i = 0; i < 8; ++i)
#pragma unroll
        for (int j = 0; j < 8; ++j) acc2[i][j] += FA[(i * 8 + j) * 64 + lane];
    }
    if (wv == 2) {
#pragma unroll
      for (int i = 0; i < 8; ++i)
#pragma unroll
        for (int j = 0; j < 8; ++j) acc2[i][j] += FB[(i * 8 + j) * 64 + lane];
    }
    __syncthreads();
    if (wv == 2) {
#pragma unroll
      for (int i = 0; i < 8; ++i)
#pragma unroll
        for (int j = 0; j < 8; ++j) FA[(i * 8 + j) * 64 + lane] = acc2[i][j];
    }
    __syncthreads();
    if (wv == 0) {
      // final sums, producer-lane-contiguous: kS[lane][idx] stride 65 (2-way max)
#pragma unroll
      for (int i = 0; i < 8; ++i)
#pragma unroll
        for (int j = 0; j < 8; ++j) {
          acc2[i][j] += FA[(i * 8 + j) * 64 + lane];
          kS[lane * 65 + i * 8 + j] = acc2[i][j];
        }
    }
    __syncthreads();
    // line-coalesced atomics: each wave handles 16 contiguous U rows
    {
      float* Ub = ws + OFF_U + ((size_t)bh * 272 + mb * 64) * 64;
#pragma unroll
      for (int r = 0; r < 16; ++r) {
        const int row = wv * 16 + r;
        const int lp = (row >> 3) + 8 * (lane >> 3);      // producer lane
        const int idx = (row & 7) * 8 + (lane & 7);       // producer index
        atomicAdd(Ub + (size_t)row * 64 + lane, kS[lp * 65 + idx]);
      }
    }
    if (eo == 0) {
#pragma unroll
      for (int i = 0; i < 8; ++i)
        atomicAdd(ws + OFF_u + (size_t)bh * 272 + mb * 64 + mo * 8 + i, uacc[i]);
    }
  }
#pragma unroll
  for (int o = 32; o > 0; o >>= 1) smax = fmaxf(smax, __shfl_xor(smax, o));
  if (lane == 0) redb[wv] = smax;
  __syncthreads();
  if (t == 0) {
    const float m = fmaxf(fmaxf(redb[0], redb[1]), fmaxf(redb[2], redb[3]));
    atomicMax((unsigned*)(ws + OFF_S), fenc(m));
  }
}

// --------------------------- K3: combine -> ctx_ext, Sc, Sk -----------------
__global__ __launch_bounds__(256) void combine_kernel(float* __restrict__ ws) {
  __shared__ float red[256];
  const int t = threadIdx.x;
  const int bh = blockIdx.x;
  const float S = fdec(((unsigned*)(ws + OFF_S))[0]);
  const float es = __expf(-S);
  const int e = t & 63, mr = t >> 6;
  const float svv = ws[OFF_SV + bh * 64 + e];
  float scp = 0.f;
  for (int mm = mr; mm < 272; mm += 4) {
    float val = 0.f;
    if (mm < 266)
      val = (es * ws[OFF_U + ((size_t)bh * 272 + mm) * 64 + e] + EPSV * svv) * INV_L;
    ws[OFF_CTX + ((size_t)bh * 272 + mm) * 68 + e] = val;
    scp += val;
  }
  red[t] = scp;
  __syncthreads();
  if (t < 64) ws[OFF_SC + bh * 64 + t] = red[t] + red[t + 64] + red[t + 128] + red[t + 192];
  __syncthreads();
  float skp = 0.f;
  for (int mm = t; mm < 272; mm += 256) {
    float km = 0.f;
    if (mm < 266) km = es * ws[OFF_u + (size_t)bh * 272 + mm] * INV_L + EPSV;
    float* cx = ws + OFF_CTX + ((size_t)bh * 272 + mm) * 68;
    cx[64] = km; cx[65] = 0.f; cx[66] = 0.f; cx[67] = 0.f;
    skp += km;
  }
  red[t] = skp;
  __syncthreads();
  for (int s = 128; s > 0; s >>= 1) {
    if (t < s) red[t] += red[t + s];
    __syncthreads();
  }
  if (t == 0) ws[OFF_SK + bh] = red[0];
}

// --------------------------- K4: q-pass -> out ------------------------------
// LDS: uni = qS[32][68] + PTt[64][16]@2176 during GEMM1, then qph[32][272],
// then reduction scratch for GEMM2.
__global__ __launch_bounds__(256) void pass_q(const float* __restrict__ qg,
                                              float* __restrict__ outg,
                                              const float* __restrict__ ws) {
  __shared__ __align__(16) float uni[8704];
  __shared__ float diagS[32];
  __shared__ unsigned rmx[32];
  __shared__ float Bl[32];

  const int t = threadIdx.x;
  const int nt = blockIdx.x, bh = blockIdx.y;
  const int lane = t & 63, wv = t >> 6;
  const float* qgp = qg + ((size_t)bh * 4096 + (size_t)nt * 32) * 64;

  if (t < 32) rmx[t] = 0x007FFFFFu; // enc(-inf)

  // stage qS[32][68] via GLDS (rows wv*8..wv*8+7); qS occupies uni[0..2172)
#pragma unroll
  for (int r = 0; r < 8; ++r)
    glds4(qgp + (wv * 8 + r) * 64 + lane, uni + (wv * 8 + r) * 68);
  // stage tail PT[64][16] into uni[2176..3200)
  {
    const int td = t >> 2, j4 = t & 3;
    *(float4*)(uni + 2176 + td * 16 + j4 * 4) =
        *(const float4*)(ws + OFF_PT + (size_t)td * 272 + 256 + j4 * 4);
  }
  __syncthreads();

  // diag pre-phase: row t>>3 (32 rows), eighth t&7
  {
    const int dr = t >> 3, d8 = t & 7;
    const float4 s0 = *(const float4*)(uni + dr * 68 + d8 * 8);
    const float4 s1 = *(const float4*)(uni + dr * 68 + d8 * 8 + 4);
    float s = s0.x * s0.x;
    s = fmaf(s0.y, s0.y, s); s = fmaf(s0.z, s0.z, s); s = fmaf(s0.w, s0.w, s);
    s = fmaf(s1.x, s1.x, s); s = fmaf(s1.y, s1.y, s); s = fmaf(s1.z, s1.z, s);
    s = fmaf(s1.w, s1.w, s);
    s += __shfl_xor(s, 1);
    s += __shfl_xor(s, 2);
    s += __shfl_xor(s, 4);
    if (d8 == 0) diagS[dr] = s * DIAG_SCALE;
  }
  __syncthreads();

  // GEMM1 main: mq = lane (64 m-quads, m<256); rows wv*8..+7; PT ring-2 (8 rows)
  const int mq = t & 63;
  float a1[8][4];
#pragma unroll
  for (int i = 0; i < 8; ++i) { a1[i][0] = a1[i][1] = a1[i][2] = a1[i][3] = 0.f; }
  {
    const float* ptm = ws + OFF_PT + mq * 4;
    float4 pfA0, pfA1, pfA2, pfA3, pfB0, pfB1, pfB2, pfB3;
    pfA0 = *(const float4*)(ptm + (size_t)0 * 272);
    pfA1 = *(const float4*)(ptm + (size_t)1 * 272);
    pfA2 = *(const float4*)(ptm + (size_t)2 * 272);
    pfA3 = *(const float4*)(ptm + (size_t)3 * 272);
    pfB0 = *(const float4*)(ptm + (size_t)4 * 272);
    pfB1 = *(const float4*)(ptm + (size_t)5 * 272);
    pfB2 = *(const float4*)(ptm + (size_t)6 * 272);
    pfB3 = *(const float4*)(ptm + (size_t)7 * 272);
#pragma unroll
    for (int tb = 0; tb < 16; tb += 2) {
      {
        const int td = tb * 4;
#pragma unroll
        for (int i = 0; i < 8; ++i) {
          const float4 q4 = *(const float4*)(uni + (wv * 8 + i) * 68 + td);
          KQ_ROW(a1[i], q4, pfA0, pfA1, pfA2, pfA3);
        }
        if (tb < 14) {
          pfA0 = *(const float4*)(ptm + (size_t)(td + 8) * 272);
          pfA1 = *(const float4*)(ptm + (size_t)(td + 9) * 272);
          pfA2 = *(const float4*)(ptm + (size_t)(td + 10) * 272);
          pfA3 = *(const float4*)(ptm + (size_t)(td + 11) * 272);
        }
      }
      {
        const int td = tb * 4 + 4;
#pragma unroll
        for (int i = 0; i < 8; ++i) {
          const float4 q4 = *(const float4*)(uni + (wv * 8 + i) * 68 + td);
          KQ_ROW(a1[i], q4, pfB0, pfB1, pfB2, pfB3);
        }
        if (tb < 14) {
          pfB0 = *(const float4*)(ptm + (size_t)(td + 8) * 272);
          pfB1 = *(const float4*)(ptm + (size_t)(td + 9) * 272);
          pfB2 = *(const float4*)(ptm + (size_t)(td + 10) * 272);
          pfB3 = *(const float4*)(ptm + (size_t)(td + 11) * 272);
        }
      }
    }
  }
  // GEMM1 tail: m_t = 256 + (t&15), rows r2, r2+1; PTt from LDS
  float at[2] = {0.f, 0.f};
  const int mtl = t & 15;
  const int mt = 256 + mtl;
  const int r2 = (t >> 4) * 2;
  {
    const float* pts = uni + 2176 + mtl;
#pragma unroll
    for (int tb = 0; tb < 16; ++tb) {
      const int td = tb * 4;
      const float4 qx4 = *(const float4*)(uni + r2 * 68 + td);
      const float4 qy4 = *(const float4*)(uni + (r2 + 1) * 68 + td);
      const float p0 = pts[(td + 0) * 16];
      const float p1 = pts[(td + 1) * 16];
      const float p2 = pts[(td + 2) * 16];
      const float p3 = pts[(td + 3) * 16];
      at[0] = fmaf(qx4.x, p0, at[0]);
      at[0] = fmaf(qx4.y, p1, at[0]);
      at[0] = fmaf(qx4.z, p2, at[0]);
      at[0] = fmaf(qx4.w, p3, at[0]);
      at[1] = fmaf(qy4.x, p0, at[1]);
      at[1] = fmaf(qy4.y, p1, at[1]);
      at[1] = fmaf(qy4.z, p2, at[1]);
      at[1] = fmaf(qy4.w, p3, at[1]);
    }
  }
  __syncthreads(); // all qS/PTt reads complete -> uni can be rewritten as qph

  // rowmax (raw qd): main butterfly + tail group-reduce, into LDS atomicMax
#pragma unroll
  for (int i = 0; i < 8; ++i) {
    float lm = fmaxf(fmaxf(a1[i][0], a1[i][1]), fmaxf(a1[i][2], a1[i][3]));
#pragma unroll
    for (int o = 32; o > 0; o >>= 1) lm = fmaxf(lm, __shfl_xor(lm, o));
    if (lane == i) atomicMax(&rmx[wv * 8 + i], fenc(lm));
  }
#pragma unroll
  for (int s = 0; s < 2; ++s) {
    float v = (mt < 266) ? at[s] : -INFINITY;
#pragma unroll
    for (int o = 8; o > 0; o >>= 1) v = fmaxf(v, __shfl_xor(v, o));
    if ((t & 15) == 0) atomicMax(&rmx[r2 + s], fenc(v));
  }
  // exp (unstabilized, diag from LDS) + store qph (stride 272)
#pragma unroll
  for (int i = 0; i < 8; ++i) {
    const int row = wv * 8 + i;
    const float dg = diagS[row];
    float4 st;
    st.x = __expf(a1[i][0] - dg);
    st.y = __expf(a1[i][1] - dg);
    st.z = __expf(a1[i][2] - dg);
    st.w = __expf(a1[i][3] - dg);
    *(float4*)(uni + row * 272 + mq * 4) = st;
  }
#pragma unroll
  for (int s = 0; s < 2; ++s) {
    const int row = r2 + s;
    uni[row * 272 + mt] = (mt < 266) ? __expf(at[s] - diagS[row]) : 0.f;
  }
  __syncthreads();

  // GEMM2: 4 rows x 4 cols x m-split(2). cq2 = e-quad, rg2 = 4-row group,
  // ms = m-half. ctx streamed from global (L2-resident) with ring-1 prefetch.
  const int cq2 = t & 15, rg2 = (t >> 4) & 7, ms = t >> 7;
  const float* ctxg = ws + OFF_CTX + (size_t)bh * 272 * 68;
  const float* crow = ctxg + cq2 * 4;
  const int mb0 = ms * 136;
  float acc[4][4];
#pragma unroll
  for (int i = 0; i < 4; ++i) { acc[i][0] = acc[i][1] = acc[i][2] = acc[i][3] = 0.f; }
  float accB[4] = {0, 0, 0, 0};
  float4 c0, c1, c2, c3, n0, n1, n2, n3;
  float cb0 = 0, cb1 = 0, cb2 = 0, cb3 = 0, nb0 = 0, nb1 = 0, nb2 = 0, nb3 = 0;
  c0 = *(const float4*)(crow + (size_t)(mb0 + 0) * 68);
  c1 = *(const float4*)(crow + (size_t)(mb0 + 1) * 68);
  c2 = *(const float4*)(crow + (size_t)(mb0 + 2) * 68);
  c3 = *(const float4*)(crow + (size_t)(mb0 + 3) * 68);
  if (cq2 == 0) {
    cb0 = ctxg[(size_t)(mb0 + 0) * 68 + 64];
    cb1 = ctxg[(size_t)(mb0 + 1) * 68 + 64];
    cb2 = ctxg[(size_t)(mb0 + 2) * 68 + 64];
    cb3 = ctxg[(size_t)(mb0 + 3) * 68 + 64];
  }
  for (int mc = 0; mc < 34; ++mc) {
    const int mm = mb0 + mc * 4;
    if (mc < 33) {
      n0 = *(const float4*)(crow + (size_t)(mm + 4) * 68);
      n1 = *(const float4*)(crow + (size_t)(mm + 5) * 68);
      n2 = *(const float4*)(crow + (size_t)(mm + 6) * 68);
      n3 = *(const float4*)(crow + (size_t)(mm + 7) * 68);
      if (cq2 == 0) {
        nb0 = ctxg[(size_t)(mm + 4) * 68 + 64];
        nb1 = ctxg[(size_t)(mm + 5) * 68 + 64];
        nb2 = ctxg[(size_t)(mm + 6) * 68 + 64];
        nb3 = ctxg[(size_t)(mm + 7) * 68 + 64];
      }
    }
    const float4 q0 = *(const float4*)(uni + (rg2 * 4 + 0) * 272 + mm);
    const float4 q1 = *(const float4*)(uni + (rg2 * 4 + 1) * 272 + mm);
    const float4 q2 = *(const float4*)(uni + (rg2 * 4 + 2) * 272 + mm);
    const float4 q3 = *(const float4*)(uni + (rg2 * 4 + 3) * 272 + mm);
    QC_ROW(acc[0], q0, c0, c1, c2, c3);
    QC_ROW(acc[1], q1, c0, c1, c2, c3);
    QC_ROW(acc[2], q2, c0, c1, c2, c3);
    QC_ROW(acc[3], q3, c0, c1, c2, c3);
    if (cq2 == 0) {
      accB[0] = fmaf(q0.x, cb0, accB[0]);
      accB[0] = fmaf(q0.y, cb1, accB[0]);
      accB[0] = fmaf(q0.z, cb2, accB[0]);
      accB[0] = fmaf(q0.w, cb3, accB[0]);
      accB[1] = fmaf(q1.x, cb0, accB[1]);
      accB[1] = fmaf(q1.y, cb1, accB[1]);
      accB[1] = fmaf(q1.z, cb2, accB[1]);
      accB[1] = fmaf(q1.w, cb3, accB[1]);
      accB[2] = fmaf(q2.x, cb0, accB[2]);
      accB[2] = fmaf(q2.y, cb1, accB[2]);
      accB[2] = fmaf(q2.z, cb2, accB[2]);
      accB[2] = fmaf(q2.w, cb3, accB[2]);
      accB[3] = fmaf(q3.x, cb0, accB[3]);
      accB[3] = fmaf(q3.y, cb1, accB[3]);
      accB[3] = fmaf(q3.z, cb2, accB[3]);
      accB[3] = fmaf(q3.w, cb3, accB[3]);
    }
    if (mc < 33) {
      c0 = n0; c1 = n1; c2 = n2; c3 = n3;
      cb0 = nb0; cb1 = nb1; cb2 = nb2; cb3 = nb3;
    }
  }

  // reduce the two m-halves through LDS (qph dead now), stride-1 layout
  __syncthreads(); // all qph reads complete
  if (ms == 1) {
    const int p = t - 128;
#pragma unroll
    for (int i = 0; i < 4; ++i)
#pragma unroll
      for (int j = 0; j < 4; ++j) uni[(i * 4 + j) * 128 + p] = acc[i][j];
    if (cq2 == 0) {
#pragma unroll
      for (int i = 0; i < 4; ++i) uni[2048 + rg2 * 4 + i] = accB[i];
    }
  }
  __syncthreads();
  if (ms == 0) {
#pragma unroll
    for (int i = 0; i < 4; ++i)
#pragma unroll
      for (int j = 0; j < 4; ++j) acc[i][j] += uni[(i * 4 + j) * 128 + t];
    if (cq2 == 0) {
#pragma unroll
      for (int i = 0; i < 4; ++i) Bl[rg2 * 4 + i] = accB[i] + uni[2048 + rg2 * 4 + i];
    }
  }
  __syncthreads(); // Bl ready

  if (ms == 0) {
    const float4 sc4 = *(const float4*)(ws + OFF_SC + bh * 64 + cq2 * 4);
    const float skv = ws[OFF_SK + bh];
    float* op = outg + ((size_t)bh * 4096 + (size_t)nt * 32) * 64;
#pragma unroll
    for (int i = 0; i < 4; ++i) {
      const int row = rg2 * 4 + i;
      const float rm = fdec(rmx[row]);
      const float tt = EPSV * __expf(rm);
      const float inv = 1.0f / (Bl[row] + tt * skv);
      float4 o;
      o.x = (acc[i][0] + tt * sc4.x) * inv;
      o.y = (acc[i][1] + tt * sc4.y) * inv;
      o.z = (acc[i][2] + tt * sc4.z) * inv;
      o.w = (acc[i][3] + tt * sc4.w) * inv;
      *(float4*)(op + row * 64 + cq2 * 4) = o;
    }
  }
}

// --------------------------- launch -----------------------------------------
extern "C" void kernel_launch(void* const* d_in, const int* in_sizes, int n_in,
                              void* d_out, int out_size, void* d_ws, size_t ws_size,
                              hipStream_t stream) {
  (void)in_sizes; (void)n_in; (void)out_size; (void)ws_size;
  const float* q = (const float*)d_in[0];
  const float* k = (const float*)d_in[1];
  const float* v = (const float*)d_in[2];
  const float* P = (const float*)d_in[3];
  float* out = (float*)d_out;
  float* ws = (float*)d_ws;

  // zero only the accumulated region [OFF_U, OFF_CTX)
  hipMemsetAsync((void*)(ws + OFF_U), 0, (OFF_CTX - OFF_U) * sizeof(float), stream);
  setup_kernel<<<68, 256, 0, stream>>>(P, ws);
  pass_k_fused<<<640, 256, 0, stream>>>(k, v, ws);
  combine_kernel<<<32, 256, 0, stream>>>(ws);
  pass_q<<<dim3(128, 32), 256, 0, stream>>>(q, out, ws);
}